// Round 7
// baseline (309.838 us; speedup 1.0000x reference)
//
#include <hip/hip_runtime.h>
#include <hip/hip_bf16.h>

typedef unsigned short ushort_t;
typedef __bf16 bf16_t;
typedef bf16_t bf16x8 __attribute__((ext_vector_type(8)));
typedef float floatx4 __attribute__((ext_vector_type(4)));
typedef ushort_t ushortx8 __attribute__((ext_vector_type(8)));

struct alignas(8) us4 { ushort_t x, y, z, w; };

__device__ __forceinline__ ushort_t f2bf(float f) {
  union { float f; unsigned int u; } v; v.f = f;
  unsigned int u = v.u;
  return (ushort_t)((u + 0x7fffu + ((u >> 16) & 1u)) >> 16);
}

__device__ __forceinline__ unsigned int pk_bf16(float a, float b) {
  __hip_bfloat162 h = __float22bfloat162_rn(float2{a, b});  // .x in low half
  union { __hip_bfloat162 h; unsigned int u; } v; v.h = h;
  return v.u;
}

__device__ __forceinline__ void async16(const void* g, void* l) {
  __builtin_amdgcn_global_load_lds(
      (const __attribute__((address_space(1))) unsigned int*)g,
      (__attribute__((address_space(3))) unsigned int*)l, 16, 0, 0);
}

#define LOG2E 1.44269504088896340736f

// ---------------- fused prep: cvt x -> bf16, transpose-cast W_qkv, W_proj ----

__global__ __launch_bounds__(256) void k_prep(const float* __restrict__ x,
                                              ushort_t* __restrict__ xb,
                                              const float* __restrict__ Wq,
                                              ushort_t* __restrict__ WqT,
                                              const float* __restrict__ Wp,
                                              ushort_t* __restrict__ WpT) {
  __shared__ float tile[32][33];
  const int bid = blockIdx.x, t = threadIdx.x;
  if (bid < 6144) {
    size_t i = ((size_t)bid * 256 + t) * 8;
    float4 a = *(const float4*)(x + i);
    float4 b = *(const float4*)(x + i + 4);
    ushortx8 o;
    o[0] = f2bf(a.x); o[1] = f2bf(a.y); o[2] = f2bf(a.z); o[3] = f2bf(a.w);
    o[4] = f2bf(b.x); o[5] = f2bf(b.y); o[6] = f2bf(b.z); o[7] = f2bf(b.w);
    *(ushortx8*)(xb + i) = o;
    return;
  }
  const float* in; ushort_t* out; int C, c0, r0;
  if (bid < 7872) {
    int b2 = bid - 6144;
    in = Wq; out = WqT; C = 2304;
    c0 = (b2 % 72) * 32; r0 = (b2 / 72) * 32;
  } else {
    int b3 = bid - 7872;
    in = Wp; out = WpT; C = 768;
    c0 = (b3 % 24) * 32; r0 = (b3 / 24) * 32;
  }
  const int tx = t & 31, ty = t >> 5;  // 32 x 8
#pragma unroll
  for (int i = 0; i < 32; i += 8)
    tile[ty + i][tx] = in[(size_t)(r0 + ty + i) * C + c0 + tx];
  __syncthreads();
#pragma unroll
  for (int i = 0; i < 32; i += 8)
    out[(size_t)(c0 + ty + i) * 768 + r0 + tx] = f2bf(tile[tx][ty + i]);
}

// ------ gemm_bt 2-stage ping-pong mainloop (128x128 tile, K=768, BK=32) -----
// 32 KB LDS -> 4 blocks/CU (occupancy was the round-6 binding constraint).
// Prefetch k+1 at top of iter k; tail vmcnt(0)+s_barrier. With the XCD swizzle
// A/B are L2-hot (~200 cyc) so a one-body prefetch distance suffices, and at
// 4 blocks/CU wall-distance stretches further. XOR-swizzle: 0 bank conflicts.
// lgkm safety at barrier: all ds_reads feed pre-barrier MFMAs (compiler waits).

__device__ __forceinline__ void gemm_pipe2(const ushort_t* __restrict__ A,
                                           const ushort_t* __restrict__ Bt,
                                           int m0, int n0,
                                           ushort_t* sA, ushort_t* sB,
                                           floatx4 acc[4][4]) {
  const int t = threadIdx.x;
  const int lane = t & 63, w = t >> 6;
  const int wr = w >> 1, wc = w & 1;
  const int lr = lane & 15, qd = lane >> 4;
  const int swz = ((t & 3) ^ ((t >> 3) & 3)) * 8;
  const ushort_t* gA = A + (size_t)(m0 + (t >> 2)) * 768 + swz;
  const ushort_t* gB = Bt + (size_t)(n0 + (t >> 2)) * 768 + swz;
  char* lA = (char*)sA + t * 16;
  char* lB = (char*)sB + t * 16;
  const int rsz = (qd ^ ((lr >> 1) & 3)) * 16;
#define ISSUE(kk, buf)                                    \
  do {                                                    \
    const int k0_ = (kk) * 32, b_ = (buf) * 8192;         \
    async16(gA + k0_, lA + b_);                           \
    async16(gA + k0_ + 64 * 768, lA + b_ + 4096);         \
    async16(gB + k0_, lB + b_);                           \
    async16(gB + k0_ + 64 * 768, lB + b_ + 4096);         \
  } while (0)
  ISSUE(0, 0);
  asm volatile("s_waitcnt vmcnt(0)" ::: "memory");
  asm volatile("s_barrier" ::: "memory");
#pragma unroll
  for (int k = 0; k < 24; ++k) {
    if (k + 1 < 24) ISSUE(k + 1, (k + 1) & 1);
    const char* cA = (const char*)sA + (k & 1) * 8192;
    const char* cB = (const char*)sB + (k & 1) * 8192;
    bf16x8 af[4], bfr[4];
#pragma unroll
    for (int i = 0; i < 4; ++i)
      af[i] = *(const bf16x8*)(cA + (wr * 64 + i * 16 + lr) * 64 + rsz);
#pragma unroll
    for (int j = 0; j < 4; ++j)
      bfr[j] = *(const bf16x8*)(cB + (wc * 64 + j * 16 + lr) * 64 + rsz);
#pragma unroll
    for (int i = 0; i < 4; ++i)
#pragma unroll
      for (int j = 0; j < 4; ++j)
        acc[i][j] = __builtin_amdgcn_mfma_f32_16x16x32_bf16(af[i], bfr[j], acc[i][j], 0, 0, 0);
    if (k + 1 < 24) {
      asm volatile("s_waitcnt vmcnt(0)" ::: "memory");
      asm volatile("s_barrier" ::: "memory");
    }
  }
#undef ISSUE
}

// ---------------- QKV GEMM + bias + zeta + scale, scatter to q/k/vt ----------------

__global__ __launch_bounds__(256, 4) void k_qkv(const ushort_t* __restrict__ xb,
                                                const ushort_t* __restrict__ WqT,
                                                const float* __restrict__ bqkv,
                                                const float* __restrict__ zeta,
                                                ushort_t* __restrict__ qb,
                                                ushort_t* __restrict__ kb,
                                                ushort_t* __restrict__ vtb) {
  __shared__ alignas(16) ushort_t sA[2 * 4096];
  __shared__ alignas(16) ushort_t sB[2 * 4096];
  floatx4 acc[4][4] = {};
  const int lin = blockIdx.x;
  const int xcd = lin & 7, idx = lin >> 3;           // idx in 0..287
  const int m0 = (xcd * 16 + (idx & 15)) * 128;      // 128 m-panels
  const int n0 = (idx >> 4) * 128;                   // 18 n-tiles
  gemm_pipe2(xb, WqT, m0, n0, sA, sB, acc);
  const int t = threadIdx.x, lane = t & 63, w = t >> 6;
  const int wr = w >> 1, wc = w & 1, lr = lane & 15, qd = lane >> 4;
  const int tq = n0 / 768;  // 0=q 1=k 2=v (tile never straddles: 768 % 128 == 0)
#pragma unroll
  for (int j = 0; j < 4; ++j) {
    int n = n0 + wc * 64 + j * 16 + lr;
    int nc = n - tq * 768;
    int h = nc >> 6, dim = n & 63;
    float bias = bqkv[n];
    float zv = zeta[nc];
    float mult = (tq == 0) ? zv * 0.125f * LOG2E : zv;
    if (tq < 2) {
      ushort_t* dst = (tq == 0) ? qb : kb;
#pragma unroll
      for (int i = 0; i < 4; ++i) {
        int mbase = m0 + wr * 64 + i * 16 + qd * 4;
#pragma unroll
        for (int r = 0; r < 4; ++r) {
          int m = mbase + r;
          int b = m >> 10, seq = m & 1023;
          dst[(((size_t)b * 12 + h) * 1024 + seq) * 64 + dim] = f2bf((acc[i][j][r] + bias) * mult);
        }
      }
    } else {
#pragma unroll
      for (int i = 0; i < 4; ++i) {
        int mbase = m0 + wr * 64 + i * 16 + qd * 4;
        int b = mbase >> 10, seq = mbase & 1023;
        us4 pk;
        pk.x = f2bf((acc[i][j][0] + bias) * mult);
        pk.y = f2bf((acc[i][j][1] + bias) * mult);
        pk.z = f2bf((acc[i][j][2] + bias) * mult);
        pk.w = f2bf((acc[i][j][3] + bias) * mult);
        *(us4*)&vtb[(((size_t)b * 12 + h) * 64 + dim) * 1024 + seq] = pk;
      }
    }
  }
}

// ---------------- flash attention v5 ----------------
// LDS cut to EXACTLY 40 KB -> 4 blocks/CU: sK 16K [0) + per-wave sP 4x2K
// [16384) + sV 16K [24576). Mask in registers (loaded with the DMA batch,
// applied as cndmask-to-zero AFTER exp — exact same semantics as -inf logit).
// sP per-wave 2 KB: PV runs per 32-key kk-group right after that group's exp;
// chunk-major layout (plane=16B chunk of 32 keys, row=qrow) — write uint2 at
// plane (ms2*2+(qd>>1)), read b128 plane qd. Same-wave DS in-order => reuse safe.

__global__ __launch_bounds__(256, 4) void k_attn(const ushort_t* __restrict__ qg,
                                                 const ushort_t* __restrict__ kg,
                                                 const ushort_t* __restrict__ vg,
                                                 const unsigned char* __restrict__ mask,
                                                 ushort_t* __restrict__ ob) {
  __shared__ alignas(16) char smem[40960];
  char* sV = smem + 24576;
  const int t = threadIdx.x, lane = t & 63, w = t >> 6;
  const int lr = lane & 15, qd = lane >> 4;
  const int lin = blockIdx.x;
  const int bh = (lin & 7) + 8 * (lin >> 6);
  const int qt = (lin >> 3) & 7;
  const int b = bh / 12, h = bh % 12;
  const int qrow0 = qt * 128 + w * 32;
  const ushort_t* qp = qg + (size_t)bh * 65536;
  const ushort_t* kp = kg + (size_t)bh * 65536;
  const ushort_t* vp = vg + (size_t)bh * 65536;
  const unsigned char* mp = mask + b * 1024;

  bf16x8 qf[2][2];
#pragma unroll
  for (int ns = 0; ns < 2; ++ns)
#pragma unroll
    for (int kk = 0; kk < 2; ++kk)
      qf[ns][kk] = *(const bf16x8*)(qp + (size_t)(qrow0 + ns * 16 + lr) * 64 + kk * 32 + qd * 8);

  floatx4 o[4][2] = {};
  float lst[2] = {0.f, 0.f};
  char* sPw = smem + 16384 + w * 2048;

  for (int kt = 0; kt < 8; ++kt) {
    __syncthreads();
    const ushort_t* kpt = kp + kt * 8192;
#pragma unroll
    for (int it = 0; it < 4; ++it) {
      int p = it * 256 + t;
      int r = p >> 3, cs = (p & 7) ^ (r & 7);
      async16(kpt + r * 64 + cs * 8, smem + p * 16);
    }
    const ushort_t* vpt = vp + kt * 128;
#pragma unroll
    for (int it = 0; it < 4; ++it) {
      int p = it * 256 + t;
      int r = p >> 4, cs = (p & 15) ^ (r & 15);
      async16(vpt + (size_t)r * 1024 + cs * 8, sV + p * 16);
    }
    // mask words for this kt (4 keys per lane per (hh,ms)); complete under vmcnt(0)
    unsigned int mw[2][4];
#pragma unroll
    for (int mh = 0; mh < 2; ++mh)
#pragma unroll
      for (int ms = 0; ms < 4; ++ms)
        mw[mh][ms] = *(const unsigned int*)(mp + kt * 128 + (mh * 4 + ms) * 16 + qd * 4);
    asm volatile("s_waitcnt vmcnt(0)" ::: "memory");
    __syncthreads();

#pragma unroll
    for (int hh = 0; hh < 2; ++hh) {
      // S^T quarter: 64 keys (4 msub) x 32 qrows (2 nsub)
      floatx4 s[4][2] = {};
#pragma unroll
      for (int kk = 0; kk < 2; ++kk) {
#pragma unroll
        for (int ms = 0; ms < 4; ++ms) {
          bf16x8 ak = *(const bf16x8*)(smem + ((hh * 4 + ms) * 16 + lr) * 128 +
                                       ((kk * 4 + qd) ^ (lr & 7)) * 16);
#pragma unroll
          for (int ns = 0; ns < 2; ++ns)
            s[ms][ns] = __builtin_amdgcn_mfma_f32_16x16x32_bf16(ak, qf[ns][kk], s[ms][ns], 0, 0, 0);
        }
      }
      // per 32-key group: exp -> sP -> PV
#pragma unroll
      for (int kk = 0; kk < 2; ++kk) {
#pragma unroll
        for (int ms2 = 0; ms2 < 2; ++ms2) {
          const int ms = kk * 2 + ms2;
          const unsigned int m4 = mw[hh][ms];
#pragma unroll
          for (int ns = 0; ns < 2; ++ns) {
            float p0 = __builtin_amdgcn_exp2f(s[ms][ns][0]);
            float p1 = __builtin_amdgcn_exp2f(s[ms][ns][1]);
            float p2 = __builtin_amdgcn_exp2f(s[ms][ns][2]);
            float p3 = __builtin_amdgcn_exp2f(s[ms][ns][3]);
            p0 = (m4 & 0x000000ffu) ? 0.f : p0;
            p1 = (m4 & 0x0000ff00u) ? 0.f : p1;
            p2 = (m4 & 0x00ff0000u) ? 0.f : p2;
            p3 = (m4 & 0xff000000u) ? 0.f : p3;
            lst[ns] += (p0 + p1) + (p2 + p3);
            uint2 pk;
            pk.x = pk_bf16(p0, p1);
            pk.y = pk_bf16(p2, p3);
            *(uint2*)(sPw + (ms2 * 2 + (qd >> 1)) * 512 +
                      (ns * 16 + lr) * 16 + (qd & 1) * 8) = pk;
          }
        }
        asm volatile("s_waitcnt lgkmcnt(0)" ::: "memory");  // wave-local P visible
        bf16x8 pb[2];
#pragma unroll
        for (int ns = 0; ns < 2; ++ns)
          pb[ns] = *(const bf16x8*)(sPw + qd * 512 + (ns * 16 + lr) * 16);
#pragma unroll
        for (int ds = 0; ds < 4; ++ds) {
          bf16x8 av = *(const bf16x8*)(sV + (ds * 16 + lr) * 256 +
                                       ((hh * 8 + kk * 4 + qd) ^ lr) * 16);
#pragma unroll
          for (int ns = 0; ns < 2; ++ns)
            o[ds][ns] = __builtin_amdgcn_mfma_f32_16x16x32_bf16(av, pb[ns], o[ds][ns], 0, 0, 0);
        }
      }
    }
  }
#pragma unroll
  for (int ns = 0; ns < 2; ++ns) {
    lst[ns] += __shfl_xor(lst[ns], 16);
    lst[ns] += __shfl_xor(lst[ns], 32);
  }
#pragma unroll
  for (int ns = 0; ns < 2; ++ns) {
    float rl = 1.0f / lst[ns];
    size_t row = (size_t)(b * 1024 + qrow0 + ns * 16 + lr) * 768 + h * 64;
#pragma unroll
    for (int ds = 0; ds < 4; ++ds) {
      uint2 ov;
      ov.x = pk_bf16(o[ds][ns][0] * rl, o[ds][ns][1] * rl);
      ov.y = pk_bf16(o[ds][ns][2] * rl, o[ds][ns][3] * rl);
      *(uint2*)&ob[row + ds * 16 + qd * 4] = ov;
    }
  }
}

// ---------------- output projection ----------------

__global__ __launch_bounds__(256, 4) void k_proj(const ushort_t* __restrict__ ob,
                                                 const ushort_t* __restrict__ WpT,
                                                 const float* __restrict__ bproj,
                                                 float* __restrict__ out) {
  __shared__ alignas(16) ushort_t sA[2 * 4096];
  __shared__ alignas(16) ushort_t sB[2 * 4096];
  floatx4 acc[4][4] = {};
  const int lin = blockIdx.x;
  const int xcd = lin & 7, idx = lin >> 3;           // idx in 0..95
  const int m0 = (xcd * 16 + (idx & 15)) * 128;
  const int n0 = (idx >> 4) * 128;                   // 6 n-tiles
  gemm_pipe2(ob, WpT, m0, n0, sA, sB, acc);
  const int t = threadIdx.x, lane = t & 63, w = t >> 6;
  const int wr = w >> 1, wc = w & 1, lr = lane & 15, qd = lane >> 4;
#pragma unroll
  for (int j = 0; j < 4; ++j) {
    int n = n0 + wc * 64 + j * 16 + lr;
    float bias = bproj[n];
#pragma unroll
    for (int i = 0; i < 4; ++i) {
      int mbase = m0 + wr * 64 + i * 16 + qd * 4;
#pragma unroll
      for (int r = 0; r < 4; ++r)
        out[(size_t)(mbase + r) * 768 + n] = acc[i][j][r] + bias;
    }
  }
}

// ---------------- launch ----------------

extern "C" void kernel_launch(void* const* d_in, const int* in_sizes, int n_in,
                              void* d_out, int out_size, void* d_ws, size_t ws_size,
                              hipStream_t stream) {
  const float* x = (const float*)d_in[0];
  const float* bqkv = (const float*)d_in[2];
  const float* zeta = (const float*)d_in[3];
  const float* bproj = (const float*)d_in[5];
  const unsigned char* mask = (const unsigned char*)d_in[6];
  float* out = (float*)d_out;
  char* ws = (char*)d_ws;
  ushort_t* xb  = (ushort_t*)(ws);              // 16384x768 bf16
  ushort_t* WqT = (ushort_t*)(ws + 25165824);   // 2304x768 bf16
  ushort_t* WpT = (ushort_t*)(ws + 28704768);   // 768x768 bf16
  ushort_t* qb  = (ushort_t*)(ws + 29884416);   // (B,H,N,d) bf16
  ushort_t* kb  = (ushort_t*)(ws + 55050240);   // (B,H,N,d) bf16
  ushort_t* vtb = (ushort_t*)(ws + 80216064);   // (B,H,d,N) bf16
  ushort_t* ob  = xb;  // xb dead after k_qkv; reuse as attention output

  k_prep<<<dim3(8448), dim3(256), 0, stream>>>(x, xb, (const float*)d_in[1], WqT,
                                               (const float*)d_in[4], WpT);
  k_qkv<<<dim3(2304), dim3(256), 0, stream>>>(xb, WqT, bqkv, zeta, qb, kb, vtb);
  k_attn<<<dim3(1536), dim3(256), 0, stream>>>(qb, kb, vtb, mask, ob);
  k_proj<<<dim3(768), dim3(256), 0, stream>>>(ob, WpT, bproj, out);
}